// Round 2
// baseline (417.351 us; speedup 1.0000x reference)
//
#include <hip/hip_runtime.h>

#define LSEQ 4096
#define NPOS 8192

__device__ __forceinline__ float silu_f(float x){ return x / (1.f + __expf(-x)); }
__device__ __forceinline__ float softplus_f(float x){
  return fmaxf(x, 0.f) + log1pf(__expf(-fabsf(x)));
}

// ---- transpose weights, A = -exp(A_log) --------------------------------
__global__ __launch_bounds__(256) void k_prep(
    const float* __restrict__ ipw, const float* __restrict__ xpw,
    const float* __restrict__ dtw, const float* __restrict__ opw,
    const float* __restrict__ w1, const float* __restrict__ w2,
    const float* __restrict__ w3, const float* __restrict__ alog,
    float* __restrict__ ipT, float* __restrict__ xpT,
    float* __restrict__ dtT, float* __restrict__ opT,
    float* __restrict__ w1T, float* __restrict__ w2T,
    float* __restrict__ w3T, float* __restrict__ Aneg)
{
  int t = blockIdx.x * 256 + threadIdx.x;
  if (t < 16384){ int o = t >> 6, c = t & 63; ipT[c * 256 + o] = ipw[t]; }
  if (t < 8192){ int o = t >> 7, d = t & 127; xpT[d * 64 + o] = xpw[t]; }
  if (t < 4096){ int d = t >> 5, r = t & 31; dtT[r * 128 + d] = dtw[t]; }
  if (t < 8192){ int o = t >> 7, d = t & 127; opT[d * 64 + o] = opw[t]; }
  if (t < 4096){ int o = t >> 6, c = t & 63;
                 w1T[c*64+o] = w1[t]; w2T[c*64+o] = w2[t]; w3T[c*64+o] = w3[t]; }
  if (t < 2048){ Aneg[t] = -__expf(alog[t]); }
}

// ---- input 1x1 convs: [B,C,L] -> [N,64] fp32 (position-major) ----------
__global__ __launch_bounds__(256) void k_convin(
    const float* __restrict__ rgb, const float* __restrict__ dte,
    const float* __restrict__ w1T, const float* __restrict__ b1,
    const float* __restrict__ w2T, const float* __restrict__ b2,
    float* __restrict__ rgbp, float* __restrict__ dtep)
{
  int gw = (blockIdx.x * 256 + threadIdx.x) >> 6;   // one wave per (image,pos)
  int lane = threadIdx.x & 63;
  int which = gw >> 13;
  int n = gw & 8191;
  const float* x  = which ? dte : rgb;
  const float* wT = which ? w2T : w1T;
  const float* bb = which ? b2 : b1;
  float* o = which ? dtep : rgbp;
  int b = n >> 12, l = n & 4095;
  const float* xp = x + (size_t)b * 262144 + l;
  float acc = bb[lane];
  for (int c = 0; c < 64; c++)
    acc += wT[c*64 + lane] * xp[(size_t)c * 4096];
  o[(size_t)n*64 + lane] = acc;
}

// ---- block-0 pre: rmsnorm + in_proj (one wave = 8 positions) -----------
__global__ __launch_bounds__(256) void k_pre(
    const float* __restrict__ xin, const float* __restrict__ normw,
    const float* __restrict__ ipT,
    float* __restrict__ xn, float* __restrict__ xcp, float* __restrict__ zs)
{
  __shared__ __align__(16) float xnl[4][8][64];
  const int wv = threadIdx.x >> 6, lane = threadIdx.x & 63;
  const int n0 = (blockIdx.x * 4 + wv) * 8;
  float nw = normw[lane];
  #pragma unroll 1
  for (int p = 0; p < 8; p++){
    int n = n0 + p;
    float v = xin[(size_t)n*64 + lane];
    float ss = v * v;
    for (int m = 32; m > 0; m >>= 1) ss += __shfl_xor(ss, m);
    v = v * rsqrtf(ss * (1.f/64.f) + 1e-5f) * nw;
    xn[(size_t)n*64 + lane] = v;
    xnl[wv][p][lane] = v;
  }
  float ac[8][4] = {};
  for (int c = 0; c < 64; c++){
    float w0 = ipT[c*256 + lane],       w1 = ipT[c*256 + 64 + lane];
    float w2 = ipT[c*256 + 128 + lane], w3 = ipT[c*256 + 192 + lane];
    #pragma unroll
    for (int p = 0; p < 8; p++){
      float xv = xnl[wv][p][c];
      ac[p][0] += w0*xv; ac[p][1] += w1*xv; ac[p][2] += w2*xv; ac[p][3] += w3*xv;
    }
  }
  #pragma unroll
  for (int p = 0; p < 8; p++){
    int n = n0 + p;
    xcp[(size_t)n*128 + lane]      = ac[p][0];
    xcp[(size_t)n*128 + 64 + lane] = ac[p][1];
    zs[(size_t)n*128 + lane]       = silu_f(ac[p][2]);
    zs[(size_t)n*128 + 64 + lane]  = silu_f(ac[p][3]);
  }
}

// ---- one Mamba block (+ fused next-block rmsnorm/in_proj) --------------
// one wave = 4 positions; lane owns d0=lane, d1=64+lane of d_inner
__global__ __launch_bounds__(256) void k_step(
    const float* __restrict__ xcpA, float* __restrict__ xcpB,
    float* __restrict__ zs, float* __restrict__ xn,
    float* __restrict__ h, const float* __restrict__ base_next,
    const float* __restrict__ xpT, const float* __restrict__ dtT,
    const float* __restrict__ opT, const float* __restrict__ Aneg,
    const float* __restrict__ c1w, const float* __restrict__ c1b,
    const float* __restrict__ dtb, const float* __restrict__ Dpw,
    const float* __restrict__ normw, const float* __restrict__ ipT,
    int hasH, int fusePre)
{
  __shared__ __align__(16) float xcl[4][4][128];
  __shared__ __align__(16) float dbl[4][4][64];
  __shared__ __align__(16) float yzl[4][4][128];
  __shared__ __align__(16) float xnl[4][4][64];
  const int wv = threadIdx.x >> 6, lane = threadIdx.x & 63;
  const int n0 = (blockIdx.x * 4 + wv) * 4;
  const int d0 = lane, d1 = 64 + lane;

  float cw00 = c1w[d0*3+0], cw01 = c1w[d0*3+1], cw02 = c1w[d0*3+2];
  float cw10 = c1w[d1*3+0], cw11 = c1w[d1*3+1], cw12 = c1w[d1*3+2];
  float cb0 = c1b[d0], cb1 = c1b[d1];

  // depthwise conv (radius 1 over l within batch) + silu
  float xc[4][2];
  #pragma unroll
  for (int p = 0; p < 4; p++){
    int n = n0 + p, l = n & (LSEQ-1);
    const float* xr = xcpA + (size_t)n * 128;
    float am0 = (l > 0) ? xr[d0 - 128] : 0.f;
    float am1 = (l > 0) ? xr[d1 - 128] : 0.f;
    float a00 = xr[d0], a01 = xr[d1];
    float ap0 = (l < LSEQ-1) ? xr[d0 + 128] : 0.f;
    float ap1 = (l < LSEQ-1) ? xr[d1 + 128] : 0.f;
    float v0 = silu_f(cw00*am0 + cw01*a00 + cw02*ap0 + cb0);
    float v1 = silu_f(cw10*am1 + cw11*a01 + cw12*ap1 + cb1);
    xc[p][0] = v0; xc[p][1] = v1;
    xcl[wv][p][d0] = v0; xcl[wv][p][d1] = v1;
  }

  // x_proj: dbc[o=lane] = sum_d xpw[o][d]*xc[d]
  float xa0=0.f, xa1=0.f, xa2=0.f, xa3=0.f;
  for (int d = 0; d < 128; d++){
    float w = xpT[d*64 + lane];
    xa0 += w * xcl[wv][0][d];
    xa1 += w * xcl[wv][1][d];
    xa2 += w * xcl[wv][2][d];
    xa3 += w * xcl[wv][3][d];
  }
  dbl[wv][0][lane]=xa0; dbl[wv][1][lane]=xa1; dbl[wv][2][lane]=xa2; dbl[wv][3][lane]=xa3;

  // dt_proj + softplus for lane's two d's
  float tb0 = dtb[d0], tb1 = dtb[d1];
  float da[4][2];
  #pragma unroll
  for (int p = 0; p < 4; p++){ da[p][0]=tb0; da[p][1]=tb1; }
  for (int r = 0; r < 32; r++){
    float w0 = dtT[r*128 + d0];
    float w1 = dtT[r*128 + d1];
    #pragma unroll
    for (int p = 0; p < 4; p++){
      float bv = dbl[wv][p][r];
      da[p][0] += w0 * bv; da[p][1] += w1 * bv;
    }
  }
  float dl[4][2];
  #pragma unroll
  for (int p = 0; p < 4; p++){ dl[p][0]=softplus_f(da[p][0]); dl[p][1]=softplus_f(da[p][1]); }

  float an0[16], an1[16];
  {
    const float4* A0 = (const float4*)(Aneg + d0*16);
    const float4* A1 = (const float4*)(Aneg + d1*16);
    #pragma unroll
    for (int q = 0; q < 4; q++){
      float4 a = A0[q]; an0[q*4+0]=a.x; an0[q*4+1]=a.y; an0[q*4+2]=a.z; an0[q*4+3]=a.w;
      float4 b = A1[q]; an1[q*4+0]=b.x; an1[q*4+1]=b.y; an1[q*4+2]=b.z; an1[q*4+3]=b.w;
    }
  }
  float dp0 = Dpw[d0], dp1 = Dpw[d1];

  // h update (fp32 in global = d_out tail, streamed) + y + yz
  #pragma unroll 1
  for (int p = 0; p < 4; p++){
    int n = n0 + p;
    float Bm[16], Cm[16];
    {
      const float4* bb = (const float4*)&dbl[wv][p][32];
      const float4* cc = (const float4*)&dbl[wv][p][48];
      #pragma unroll
      for (int q = 0; q < 4; q++){
        float4 a = bb[q]; Bm[q*4+0]=a.x; Bm[q*4+1]=a.y; Bm[q*4+2]=a.z; Bm[q*4+3]=a.w;
        float4 b = cc[q]; Cm[q*4+0]=b.x; Cm[q*4+1]=b.y; Cm[q*4+2]=b.z; Cm[q*4+3]=b.w;
      }
    }
    float* hp0 = h + ((size_t)n*2048 + (size_t)d0*16);
    float* hp1 = h + ((size_t)n*2048 + (size_t)d1*16);
    float h0[16], h1[16];
    if (hasH){
      #pragma unroll
      for (int q = 0; q < 4; q++){
        float4 v = ((const float4*)hp0)[q];
        h0[q*4+0]=v.x; h0[q*4+1]=v.y; h0[q*4+2]=v.z; h0[q*4+3]=v.w;
        float4 w = ((const float4*)hp1)[q];
        h1[q*4+0]=w.x; h1[q*4+1]=w.y; h1[q*4+2]=w.z; h1[q*4+3]=w.w;
      }
    } else {
      #pragma unroll
      for (int s = 0; s < 16; s++){ h0[s]=0.f; h1[s]=0.f; }
    }
    float y0 = 0.f, y1 = 0.f;
    float dl0 = dl[p][0], dl1 = dl[p][1];
    float bx0 = dl0 * xc[p][0], bx1 = dl1 * xc[p][1];
    #pragma unroll
    for (int s = 0; s < 16; s++){
      h0[s] = __expf(dl0*an0[s])*h0[s] + bx0*Bm[s];
      y0 += h0[s]*Cm[s];
      h1[s] = __expf(dl1*an1[s])*h1[s] + bx1*Bm[s];
      y1 += h1[s]*Cm[s];
    }
    #pragma unroll
    for (int q = 0; q < 4; q++){
      float4 v; v.x=h0[q*4+0]; v.y=h0[q*4+1]; v.z=h0[q*4+2]; v.w=h0[q*4+3];
      ((float4*)hp0)[q] = v;
      float4 w; w.x=h1[q*4+0]; w.y=h1[q*4+1]; w.z=h1[q*4+2]; w.w=h1[q*4+3];
      ((float4*)hp1)[q] = w;
    }
    y0 += dp0 * xc[p][0];
    y1 += dp1 * xc[p][1];
    yzl[wv][p][d0] = y0 * zs[(size_t)n*128 + d0];
    yzl[wv][p][d1] = y1 * zs[(size_t)n*128 + d1];
  }

  // out_proj: out[o=lane] = sum_d opw[o][d]*(y*silu(z))[d]
  float oa[4] = {0.f,0.f,0.f,0.f};
  for (int d = 0; d < 128; d++){
    float w = opT[d*64 + lane];
    oa[0] += w * yzl[wv][0][d];
    oa[1] += w * yzl[wv][1][d];
    oa[2] += w * yzl[wv][2][d];
    oa[3] += w * yzl[wv][3][d];
  }

  float nw = normw[lane];
  if (fusePre){
    // next input = base + (out_proj + xn); then rmsnorm + in_proj for next block
    #pragma unroll 1
    for (int p = 0; p < 4; p++){
      int n = n0 + p;
      float v = oa[p] + xn[(size_t)n*64 + lane] + base_next[(size_t)n*64 + lane];
      float ss = v * v;
      for (int m = 32; m > 0; m >>= 1) ss += __shfl_xor(ss, m);
      v = v * rsqrtf(ss * (1.f/64.f) + 1e-5f) * nw;
      xn[(size_t)n*64 + lane] = v;
      xnl[wv][p][lane] = v;
    }
    float ac[4][4] = {};
    for (int c = 0; c < 64; c++){
      float w0 = ipT[c*256 + lane],       w1 = ipT[c*256 + 64 + lane];
      float w2 = ipT[c*256 + 128 + lane], w3 = ipT[c*256 + 192 + lane];
      #pragma unroll
      for (int p = 0; p < 4; p++){
        float xv = xnl[wv][p][c];
        ac[p][0] += w0*xv; ac[p][1] += w1*xv; ac[p][2] += w2*xv; ac[p][3] += w3*xv;
      }
    }
    #pragma unroll
    for (int p = 0; p < 4; p++){
      int n = n0 + p;
      xcpB[(size_t)n*128 + lane]      = ac[p][0];
      xcpB[(size_t)n*128 + 64 + lane] = ac[p][1];
      zs[(size_t)n*128 + lane]        = silu_f(ac[p][2]);
      zs[(size_t)n*128 + 64 + lane]   = silu_f(ac[p][3]);
    }
  } else {
    // last block: out6[n][c] = out_proj + xn   (consumed by conv3)
    #pragma unroll
    for (int p = 0; p < 4; p++){
      int n = n0 + p;
      xcpB[(size_t)n*64 + lane] = oa[p] + xn[(size_t)n*64 + lane];
    }
  }
}

// ---- final conv1x1, transpose [N,64] -> [B,64,L] -----------------------
__global__ __launch_bounds__(256) void k_conv3(
    const float* __restrict__ out6, const float* __restrict__ w3T,
    const float* __restrict__ b3, float* __restrict__ out)
{
  __shared__ __align__(16) float t[64][65];
  const int tid = threadIdx.x;
  const int n0 = blockIdx.x * 64;
  #pragma unroll
  for (int i = 0; i < 16; i++){
    int idx = tid + 256*i;
    int r = idx >> 6, c = idx & 63;
    t[r][c] = out6[(size_t)(n0 + r)*64 + c];
  }
  __syncthreads();
  const int i = tid & 63;
  const int cb = (tid >> 6) * 16;
  float acc[16];
  #pragma unroll
  for (int j = 0; j < 16; j++) acc[j] = b3[cb + j];
  for (int o = 0; o < 64; o++){
    float xv = t[i][o];
    #pragma unroll
    for (int j = 0; j < 16; j++) acc[j] += w3T[o*64 + cb + j] * xv;
  }
  const int b = n0 >> 12;
  const int l = (n0 & 4095) + i;
  #pragma unroll
  for (int j = 0; j < 16; j++)
    out[(size_t)b*262144 + (size_t)(cb + j)*4096 + l] = acc[j];
}

extern "C" void kernel_launch(void* const* d_in, const int* in_sizes, int n_in,
                              void* d_out, int out_size, void* d_ws, size_t ws_size,
                              hipStream_t stream)
{
  const float* rgb  = (const float*)d_in[0];
  const float* dte  = (const float*)d_in[1];
  const float* w1   = (const float*)d_in[2];
  const float* b1   = (const float*)d_in[3];
  const float* w2   = (const float*)d_in[4];
  const float* b2   = (const float*)d_in[5];
  const float* w3   = (const float*)d_in[6];
  const float* b3   = (const float*)d_in[7];
  const float* nrm  = (const float*)d_in[8];
  const float* ipw  = (const float*)d_in[9];
  const float* c1w  = (const float*)d_in[10];
  const float* c1b  = (const float*)d_in[11];
  const float* xpw  = (const float*)d_in[12];
  const float* dtw  = (const float*)d_in[13];
  const float* dtb  = (const float*)d_in[14];
  const float* alog = (const float*)d_in[15];
  const float* Dpw  = (const float*)d_in[16];
  const float* opw  = (const float*)d_in[17];

  float* out  = (float*)d_out;
  float* hbuf = out + 524288;         // h output region doubles as running state

  float* ws   = (float*)d_ws;
  float* rgbp = ws;                   // [N,64]
  float* dtep = ws + 524288;          // [N,64]
  float* xnb  = ws + 1048576;         // [N,64]  normed input (residual)
  float* zsb  = ws + 1572864;         // [N,128] silu(z)
  float* xcp0 = ws + 2621440;         // [N,128] ping
  float* xcp1 = ws + 3670016;         // [N,128] pong
  float* Aneg = ws + 4718592;         // [128,16]
  float* wb   = ws + 4720640;         // transposed weights
  float* ipT = wb;                    // [64][256]
  float* xpT = wb + 16384;            // [128][64]
  float* dtT = wb + 24576;            // [32][128]
  float* opT = wb + 28672;            // [128][64]
  float* w1T = wb + 36864;            // [64][64]
  float* w2T = wb + 40960;
  float* w3T = wb + 45056;

  k_prep<<<64, 256, 0, stream>>>(ipw, xpw, dtw, opw, w1, w2, w3, alog,
                                 ipT, xpT, dtT, opT, w1T, w2T, w3T, Aneg);
  k_convin<<<4096, 256, 0, stream>>>(rgb, dte, w1T, b1, w2T, b2, rgbp, dtep);
  k_pre<<<256, 256, 0, stream>>>(rgbp, nrm, ipT, xnb, xcp0, zsb);

  float* xa[2] = {xcp0, xcp1};
  for (int k = 0; k < 6; k++){
    const float* base = (k == 5) ? nullptr : ((k & 1) ? rgbp : dtep);
    k_step<<<512, 256, 0, stream>>>(xa[k & 1], xa[(k & 1) ^ 1], zsb, xnb, hbuf, base,
                                    xpT, dtT, opT, Aneg, c1w, c1b, dtb, Dpw, nrm, ipT,
                                    (k > 0) ? 1 : 0, (k < 5) ? 1 : 0);
  }
  k_conv3<<<128, 256, 0, stream>>>(xcp0, w3T, b3, out);
}